// Round 20
// baseline (111.745 us; speedup 1.0000x reference)
//
#include <hip/hip_runtime.h>

#define S_  512
#define B_  256
#define NIN 180

typedef float v2 __attribute__((ext_vector_type(2)));

#define SSIG  -1.4426950408889634f
#define STANH -2.8853900817779268f

// ---- DPP ctrl encodings (verified on HW r5-r19) ----
#define QP_X1 0xB1
#define QP_X2 0x4E
#define QP_X3 0x1B
#define ROR4  0x124
#define ROR8  0x128

template<int CTRL>
__device__ __forceinline__ float dppf(float x) {
    return __uint_as_float((unsigned)__builtin_amdgcn_update_dpp(
        0, (int)__float_as_uint(x), CTRL, 0xF, 0xF, true));
}

#define ROTS8(h, r) do { \
    r[0] = (h); \
    r[1] = dppf<QP_X1>(h); \
    r[2] = dppf<QP_X2>(h); \
    r[3] = dppf<QP_X3>(h); \
    r[4] = dppf<ROR4>(h); \
    r[5] = dppf<QP_X1>(r[4]); \
    r[6] = dppf<QP_X2>(r[4]); \
    r[7] = dppf<QP_X3>(r[4]); \
} while (0)

// ======================= Kernel A: input GEMM (r12-verified) ==========
// Measured ~39 us in r19's 109.5 total. Unchanged.
__global__ __launch_bounds__(256) void xg_gemm(
    const float* __restrict__ x, const float* __restrict__ w,
    const float* __restrict__ bi, const float* __restrict__ bh,
    float* __restrict__ xg2)
{
    __shared__ float wt[NIN][32];
    __shared__ float bias[32];
    const int tid = threadIdx.x;
    for (int idx = tid; idx < NIN * 32; idx += 256) {
        int c = idx / NIN, i = idx - c * NIN;
        int t = c >> 2, e = c & 3;
        int g = (t >> 2) * 8 + (t & 3) * 2 + (e >> 1) + ((e & 1) << 4);
        float sc = ((g >> 3) == 2) ? STANH : SSIG;
        wt[i][c] = sc * w[g * NIN + i];
    }
    if (tid < 32) {
        int c = tid, t = c >> 2, e = c & 3;
        int g = (t >> 2) * 8 + (t & 3) * 2 + (e >> 1) + ((e & 1) << 4);
        float sc = ((g >> 3) == 2) ? STANH : SSIG;
        bias[c] = sc * (bi[g] + bh[g]);
    }
    __syncthreads();

    const int rg = tid >> 3;              // 0..31 -> 4 rows each
    const int t8 = tid & 7;
    const int s  = blockIdx.x >> 1;
    const int b0 = (blockIdx.x & 1) * 128 + rg * 4;
    const float* xr = x + ((size_t)s * B_ + b0) * NIN;

    v2 acc[4][2];
    #pragma unroll
    for (int r = 0; r < 4; ++r) { acc[r][0] = v2{0.f,0.f}; acc[r][1] = v2{0.f,0.f}; }

    float4 xb[3][4];
    #pragma unroll
    for (int d = 0; d < 3; ++d)
        #pragma unroll
        for (int r = 0; r < 4; ++r)
            xb[d][r] = *(const float4*)(xr + (size_t)r * NIN + 4 * d);

    auto GSTEP = [&](int ii, int d, bool pref) {
        float4 xn[4];
        if (pref) {
            #pragma unroll
            for (int r = 0; r < 4; ++r)
                xn[r] = *(const float4*)(xr + (size_t)r * NIN + 4 * (ii + 3));
        }
        #pragma unroll
        for (int e = 0; e < 4; ++e) {
            float4 wv = *(const float4*)&wt[4 * ii + e][t8 * 4];
            v2 wlo = v2{wv.x, wv.y}, whi = v2{wv.z, wv.w};
            #pragma unroll
            for (int r = 0; r < 4; ++r) {
                float xe = (e == 0) ? xb[d][r].x : (e == 1) ? xb[d][r].y
                         : (e == 2) ? xb[d][r].z : xb[d][r].w;
                v2 xv = v2{xe, xe};
                acc[r][0] = __builtin_elementwise_fma(wlo, xv, acc[r][0]);
                acc[r][1] = __builtin_elementwise_fma(whi, xv, acc[r][1]);
            }
        }
        if (pref) {
            #pragma unroll
            for (int r = 0; r < 4; ++r) xb[d][r] = xn[r];
        }
    };

    for (int r = 0; r < 14; ++r) {
        GSTEP(3 * r + 0, 0, true);
        GSTEP(3 * r + 1, 1, true);
        GSTEP(3 * r + 2, 2, true);
    }
    GSTEP(42, 0, false);
    GSTEP(43, 1, false);
    GSTEP(44, 2, false);

    float4 bv = *(const float4*)&bias[t8 * 4];
    const int toff = (t8 >> 2) * 16 + (t8 & 3) * 4;
    #pragma unroll
    for (int r = 0; r < 4; ++r) {
        int b = b0 + r;
        float4 o;
        o.x = acc[r][0].x + bv.x;
        o.y = acc[r][0].y + bv.y;
        o.z = acc[r][1].x + bv.z;
        o.w = acc[r][1].y + bv.w;
        size_t base = ((size_t)s * 64 + (b >> 2)) * 128 + (b & 3) * 32 + toff;
        *(float4*)(xg2 + base) = o;
    }
}

// ======================= Kernel B: 4-wave scan, 8-step phases =========
// r17-verified step math re-grouped into 64 uniform 8-step phases.
// Each consumer lags its producer by exactly 1 phase; 16-slot rings hold
// 2 phases (halves t&1 vs (t-1)&1 disjoint). Every wave: exactly 67 barriers.
__global__ __launch_bounds__(256, 1) void lstm_scan(
    const float* __restrict__ xg,
    const float* __restrict__ w_hh0,
    const float* __restrict__ w_ih1, const float* __restrict__ w_hh1,
    const float* __restrict__ b_ih1, const float* __restrict__ b_hh1,
    const float* __restrict__ w_reg, const float* __restrict__ b_reg,
    float* __restrict__ out)
{
    __shared__ float ring0[16][64];    // h0(u) at slot u&15
    __shared__ float ring1[16][128];   // a1p(u) (v2) at slot u&15
    __shared__ float ring2[16][64];    // h1(u) at slot u&15

    const int tid = threadIdx.x;
    const int wid = tid >> 6;          // 0=A1, 1=A2, 2=B, 3=proj
    const int lt  = tid & 63;
    const int j   = lt & 7;
    const int b3  = (lt >> 3) & 1;
    const int cc  = lt >> 4;
    const bool b3z = (b3 == 0);
    const int bid = blockIdx.x;        // 0..63

    const int gA = b3 * 8 + j;
    const int gB = (2 + b3) * 8 + j;
    const float sB_ = b3z ? STANH : SSIG;
    const float aB  = b3z ? 2.0f : 1.0f;
    const float bB  = b3z ? -1.0f : 0.0f;

    auto COMBINE2 = [&](float tA, float tB, float& c, float& h) {
        float m  = tA * tB;
        float mr = dppf<ROR8>(m);
        float fa = dppf<ROR8>(tA);
        float ob = dppf<ROR8>(tB);
        float ig = b3z ? m  : mr;
        float f  = b3z ? fa : tA;
        float o  = b3z ? ob : tB;
        c = __builtin_fmaf(f, c, ig);
        float th = __builtin_fmaf(2.0f, __builtin_amdgcn_rcpf(
            1.0f + __builtin_amdgcn_exp2f(STANH * c)), -1.0f);
        h = o * th;
    };

    if (wid == 0) {
        // ----- wave A1: layer-0 recurrence. 64 phase barriers + 3 idle -----
        v2 w0p[8];
        #pragma unroll
        for (int m = 0; m < 8; ++m) {
            int k = j ^ m;
            w0p[m] = v2{SSIG * w_hh0[gA * 8 + k], sB_ * w_hh0[gB * 8 + k]};
        }
        float h0p = 0.f, c0v = 0.f;

        const float* xbase = xg + (size_t)bid * 128 + lt * 2;
        v2 xq[8];
        #pragma unroll
        for (int k = 0; k < 8; ++k) xq[k] = *(const v2*)(xbase + (size_t)k * 8192);

        for (int hh = 0; hh < 64; ++hh) {
            const float* pre = xbase + (size_t)((8 * hh + 8) & 511) * 8192;
            const int sb8 = (hh & 1) * 8;
            #pragma unroll
            for (int k = 0; k < 8; ++k) {
                v2 xc = xq[k];
                xq[k] = *(const v2*)(pre + (size_t)k * 8192);
                float r0[8];
                ROTS8(h0p, r0);
                v2 a0L = __builtin_elementwise_fma(w0p[0], v2{r0[0], r0[0]}, xc);
                v2 a0H = w0p[4] * v2{r0[4], r0[4]};
                #pragma unroll
                for (int m = 1; m < 4; ++m) {
                    a0L = __builtin_elementwise_fma(w0p[m], v2{r0[m], r0[m]}, a0L);
                    a0H = __builtin_elementwise_fma(w0p[m + 4], v2{r0[m + 4], r0[m + 4]}, a0H);
                }
                v2 a0 = a0L + a0H;
                float eA = __builtin_amdgcn_exp2f(a0.x);
                float eB = __builtin_amdgcn_exp2f(a0.y);
                float tA = __builtin_amdgcn_rcpf(1.0f + eA);
                float tB = __builtin_fmaf(aB, __builtin_amdgcn_rcpf(1.0f + eB), bB);
                COMBINE2(tA, tB, c0v, h0p);
                ring0[sb8 + k][lt] = h0p;
            }
            __syncthreads();                              // #1..#64
        }
        __syncthreads();                                  // #65
        __syncthreads();                                  // #66
        __syncthreads();                                  // #67
    } else if (wid == 1) {
        // ----- wave A2: a1p = b1 + Wih1*h0. 1 idle + 64 + 2 idle -----
        v2 wi1p[8];
        #pragma unroll
        for (int m = 0; m < 8; ++m) {
            int k = j ^ m;
            wi1p[m] = v2{SSIG * w_ih1[gA * 8 + k], sB_ * w_ih1[gB * 8 + k]};
        }
        const v2 b1p = v2{SSIG * (b_ih1[gA] + b_hh1[gA]),
                          sB_  * (b_ih1[gB] + b_hh1[gB])};

        __syncthreads();                                  // #1 (t=0)
        for (int t = 1; t <= 64; ++t) {
            const int sb = ((t - 1) & 1) * 8;
            float h0v[8];
            #pragma unroll
            for (int k = 0; k < 8; ++k) h0v[k] = ring0[sb + k][lt];
            #pragma unroll
            for (int k = 0; k < 8; ++k) {
                float r0[8];
                ROTS8(h0v[k], r0);
                v2 a = __builtin_elementwise_fma(wi1p[0], v2{r0[0], r0[0]}, b1p);
                #pragma unroll
                for (int m = 1; m < 8; ++m)
                    a = __builtin_elementwise_fma(wi1p[m], v2{r0[m], r0[m]}, a);
                *(v2*)&ring1[sb + k][lt * 2] = a;
            }
            __syncthreads();                              // #2..#65
        }
        __syncthreads();                                  // #66
        __syncthreads();                                  // #67
    } else if (wid == 2) {
        // ----- wave B: layer-1 recurrence -> ring2. 2 idle + 64 + 1 idle ----
        v2 wh1p[8];
        #pragma unroll
        for (int m = 0; m < 8; ++m) {
            int k = j ^ m;
            wh1p[m] = v2{SSIG * w_hh1[gA * 8 + k], sB_ * w_hh1[gB * 8 + k]};
        }
        float h1p = 0.f, c1v = 0.f;

        __syncthreads();                                  // #1
        __syncthreads();                                  // #2
        for (int t = 2; t <= 65; ++t) {
            const int sb = (t & 1) * 8;                   // half (t-2)&1
            v2 a1in[8];
            #pragma unroll
            for (int k = 0; k < 8; ++k) a1in[k] = *(const v2*)&ring1[sb + k][lt * 2];
            #pragma unroll
            for (int k = 0; k < 8; ++k) {
                float r1[8];
                ROTS8(h1p, r1);
                v2 aL = __builtin_elementwise_fma(wh1p[0], v2{r1[0], r1[0]}, a1in[k]);
                v2 aH = wh1p[4] * v2{r1[4], r1[4]};
                #pragma unroll
                for (int m = 1; m < 4; ++m) {
                    aL = __builtin_elementwise_fma(wh1p[m], v2{r1[m], r1[m]}, aL);
                    aH = __builtin_elementwise_fma(wh1p[m + 4], v2{r1[m + 4], r1[m + 4]}, aH);
                }
                v2 a1 = aL + aH;
                float eA = __builtin_amdgcn_exp2f(a1.x);
                float eB = __builtin_amdgcn_exp2f(a1.y);
                float tA = __builtin_amdgcn_rcpf(1.0f + eA);
                float tB = __builtin_fmaf(aB, __builtin_amdgcn_rcpf(1.0f + eB), bB);
                COMBINE2(tA, tB, c1v, h1p);
                ring2[sb + k][lt] = h1p;
            }
            __syncthreads();                              // #3..#66
        }
        __syncthreads();                                  // #67
    } else {
        // ----- wave W3: projection. 3 idle + 64 -----
        float wrl[8];
        #pragma unroll
        for (int m = 0; m < 8; ++m) wrl[m] = w_reg[b3 * 8 + (j ^ m)];
        const float br  = b_reg[b3];
        const bool isl  = (j == 0);
        const int  ooff = (bid * 4 + cc) * 2 + b3;

        __syncthreads();                                  // #1
        __syncthreads();                                  // #2
        __syncthreads();                                  // #3
        for (int t = 3; t <= 66; ++t) {
            const int sb = ((t - 3) & 1) * 8;
            const int wbase = 8 * (t - 3);
            float h1v[8];
            #pragma unroll
            for (int k = 0; k < 8; ++k) h1v[k] = ring2[sb + k][lt];
            #pragma unroll
            for (int k = 0; k < 8; ++k) {
                float r1[8];
                ROTS8(h1v[k], r1);
                float pp = br;
                #pragma unroll
                for (int m = 0; m < 8; ++m) pp = __builtin_fmaf(wrl[m], r1[m], pp);
                if (isl) out[(size_t)(wbase + k) * 512 + ooff] = pp;
            }
            __syncthreads();                              // #4..#67
        }
    }
}

extern "C" void kernel_launch(void* const* d_in, const int* in_sizes, int n_in,
                              void* d_out, int out_size, void* d_ws, size_t ws_size,
                              hipStream_t stream) {
    (void)in_sizes; (void)n_in; (void)out_size; (void)ws_size;
    const float* x     = (const float*)d_in[0];
    const float* w_ih0 = (const float*)d_in[1];
    const float* w_hh0 = (const float*)d_in[2];
    const float* b_ih0 = (const float*)d_in[3];
    const float* b_hh0 = (const float*)d_in[4];
    const float* w_ih1 = (const float*)d_in[5];
    const float* w_hh1 = (const float*)d_in[6];
    const float* b_ih1 = (const float*)d_in[7];
    const float* b_hh1 = (const float*)d_in[8];
    const float* w_reg = (const float*)d_in[9];
    const float* b_reg = (const float*)d_in[10];
    float* out = (float*)d_out;
    float* xg2 = (float*)d_ws;   // 512*64*128*4 = 16 MB scratch

    xg_gemm<<<1024, 256, 0, stream>>>(x, w_ih0, b_ih0, b_hh0, xg2);
    lstm_scan<<<64, 256, 0, stream>>>(xg2, w_hh0, w_ih1, w_hh1, b_ih1, b_hh1,
                                      w_reg, b_reg, out);
}

// Round 21
// 109.459 us; speedup vs baseline: 1.0209x; 1.0209x over previous
//
#include <hip/hip_runtime.h>

#define S_  512
#define B_  256
#define NIN 180

typedef float v2 __attribute__((ext_vector_type(2)));

#define SSIG  -1.4426950408889634f
#define STANH -2.8853900817779268f

// ---- DPP ctrl encodings (verified on HW r5-r20) ----
#define QP_X1 0xB1
#define QP_X2 0x4E
#define QP_X3 0x1B
#define ROR4  0x124
#define ROR8  0x128

template<int CTRL>
__device__ __forceinline__ float dppf(float x) {
    return __uint_as_float((unsigned)__builtin_amdgcn_update_dpp(
        0, (int)__float_as_uint(x), CTRL, 0xF, 0xF, true));
}

#define ROTS8(h, r) do { \
    r[0] = (h); \
    r[1] = dppf<QP_X1>(h); \
    r[2] = dppf<QP_X2>(h); \
    r[3] = dppf<QP_X3>(h); \
    r[4] = dppf<ROR4>(h); \
    r[5] = dppf<QP_X1>(r[4]); \
    r[6] = dppf<QP_X2>(r[4]); \
    r[7] = dppf<QP_X3>(r[4]); \
} while (0)

// ======================= Kernel A: input GEMM (r12-verified) ==========
// Permuted wt columns: col c=t*4+e <-> gate g=(t>>2)*8+(t&3)*2+(e>>1)+(e&1)*16;
// float4 store at ((s*64+(b>>2))*128)+(b&3)*32+(t>>2)*16+(t&3)*4 == the
// v2-interleaved scan layout. 1024 blocks, 4 rows/thread, depth-3 ring, pk_fma.
// Measured ~39 us (r19).
__global__ __launch_bounds__(256) void xg_gemm(
    const float* __restrict__ x, const float* __restrict__ w,
    const float* __restrict__ bi, const float* __restrict__ bh,
    float* __restrict__ xg2)
{
    __shared__ float wt[NIN][32];
    __shared__ float bias[32];
    const int tid = threadIdx.x;
    for (int idx = tid; idx < NIN * 32; idx += 256) {
        int c = idx / NIN, i = idx - c * NIN;
        int t = c >> 2, e = c & 3;
        int g = (t >> 2) * 8 + (t & 3) * 2 + (e >> 1) + ((e & 1) << 4);
        float sc = ((g >> 3) == 2) ? STANH : SSIG;
        wt[i][c] = sc * w[g * NIN + i];
    }
    if (tid < 32) {
        int c = tid, t = c >> 2, e = c & 3;
        int g = (t >> 2) * 8 + (t & 3) * 2 + (e >> 1) + ((e & 1) << 4);
        float sc = ((g >> 3) == 2) ? STANH : SSIG;
        bias[c] = sc * (bi[g] + bh[g]);
    }
    __syncthreads();

    const int rg = tid >> 3;              // 0..31 -> 4 rows each
    const int t8 = tid & 7;
    const int s  = blockIdx.x >> 1;
    const int b0 = (blockIdx.x & 1) * 128 + rg * 4;
    const float* xr = x + ((size_t)s * B_ + b0) * NIN;

    v2 acc[4][2];
    #pragma unroll
    for (int r = 0; r < 4; ++r) { acc[r][0] = v2{0.f,0.f}; acc[r][1] = v2{0.f,0.f}; }

    float4 xb[3][4];
    #pragma unroll
    for (int d = 0; d < 3; ++d)
        #pragma unroll
        for (int r = 0; r < 4; ++r)
            xb[d][r] = *(const float4*)(xr + (size_t)r * NIN + 4 * d);

    auto GSTEP = [&](int ii, int d, bool pref) {
        float4 xn[4];
        if (pref) {
            #pragma unroll
            for (int r = 0; r < 4; ++r)
                xn[r] = *(const float4*)(xr + (size_t)r * NIN + 4 * (ii + 3));
        }
        #pragma unroll
        for (int e = 0; e < 4; ++e) {
            float4 wv = *(const float4*)&wt[4 * ii + e][t8 * 4];
            v2 wlo = v2{wv.x, wv.y}, whi = v2{wv.z, wv.w};
            #pragma unroll
            for (int r = 0; r < 4; ++r) {
                float xe = (e == 0) ? xb[d][r].x : (e == 1) ? xb[d][r].y
                         : (e == 2) ? xb[d][r].z : xb[d][r].w;
                v2 xv = v2{xe, xe};
                acc[r][0] = __builtin_elementwise_fma(wlo, xv, acc[r][0]);
                acc[r][1] = __builtin_elementwise_fma(whi, xv, acc[r][1]);
            }
        }
        if (pref) {
            #pragma unroll
            for (int r = 0; r < 4; ++r) xb[d][r] = xn[r];
        }
    };

    for (int r = 0; r < 14; ++r) {
        GSTEP(3 * r + 0, 0, true);
        GSTEP(3 * r + 1, 1, true);
        GSTEP(3 * r + 2, 2, true);
    }
    GSTEP(42, 0, false);
    GSTEP(43, 1, false);
    GSTEP(44, 2, false);

    float4 bv = *(const float4*)&bias[t8 * 4];
    const int toff = (t8 >> 2) * 16 + (t8 & 3) * 4;
    #pragma unroll
    for (int r = 0; r < 4; ++r) {
        int b = b0 + r;
        float4 o;
        o.x = acc[r][0].x + bv.x;
        o.y = acc[r][0].y + bv.y;
        o.z = acc[r][1].x + bv.z;
        o.w = acc[r][1].y + bv.w;
        size_t base = ((size_t)s * 64 + (b >> 2)) * 128 + (b & 3) * 32 + toff;
        *(float4*)(xg2 + base) = o;
    }
}

// ======================= Kernel B: 4-wave scan =======================
// r13..r17-verified: A1 layer0, A2 a1p, B layer1, W3 projection;
// 16-slot rings, 4-step phases, 130 barriers per wave. Measured 70.0 us.
__global__ __launch_bounds__(256, 1) void lstm_scan(
    const float* __restrict__ xg,
    const float* __restrict__ w_hh0,
    const float* __restrict__ w_ih1, const float* __restrict__ w_hh1,
    const float* __restrict__ b_ih1, const float* __restrict__ b_hh1,
    const float* __restrict__ w_reg, const float* __restrict__ b_reg,
    float* __restrict__ out)
{
    __shared__ float ring0[16][64];    // h0(u) at slot u&15
    __shared__ float ring1[16][128];   // a1p(u) (v2) at slot u&15
    __shared__ float ring2[16][64];    // h1(u) at slot u&15

    const int tid = threadIdx.x;
    const int wid = tid >> 6;          // 0=A1, 1=A2, 2=B, 3=proj
    const int lt  = tid & 63;
    const int j   = lt & 7;
    const int b3  = (lt >> 3) & 1;
    const int cc  = lt >> 4;
    const bool b3z = (b3 == 0);
    const int bid = blockIdx.x;        // 0..63

    const int gA = b3 * 8 + j;
    const int gB = (2 + b3) * 8 + j;
    const float sB_ = b3z ? STANH : SSIG;
    const float aB  = b3z ? 2.0f : 1.0f;
    const float bB  = b3z ? -1.0f : 0.0f;

    auto COMBINE2 = [&](float tA, float tB, float& c, float& h) {
        float m  = tA * tB;
        float mr = dppf<ROR8>(m);
        float fa = dppf<ROR8>(tA);
        float ob = dppf<ROR8>(tB);
        float ig = b3z ? m  : mr;
        float f  = b3z ? fa : tA;
        float o  = b3z ? ob : tB;
        c = __builtin_fmaf(f, c, ig);
        float th = __builtin_fmaf(2.0f, __builtin_amdgcn_rcpf(
            1.0f + __builtin_amdgcn_exp2f(STANH * c)), -1.0f);
        h = o * th;
    };

    if (wid == 0) {
        // ----- wave A1: layer-0 recurrence -----
        v2 w0p[8];
        #pragma unroll
        for (int m = 0; m < 8; ++m) {
            int k = j ^ m;
            w0p[m] = v2{SSIG * w_hh0[gA * 8 + k], sB_ * w_hh0[gB * 8 + k]};
        }
        float h0p = 0.f, c0v = 0.f;

        const float* xbase = xg + (size_t)bid * 128 + lt * 2;
        v2 xq[8];
        #pragma unroll
        for (int k = 0; k < 8; ++k) xq[k] = *(const v2*)(xbase + (size_t)k * 8192);

        for (int hh = 0; hh < 64; ++hh) {
            const float* pre = xbase + (size_t)((8 * hh + 8) & 511) * 8192;
            const int sb8 = (hh & 1) * 8;
            #pragma unroll
            for (int k = 0; k < 8; ++k) {
                v2 xc = xq[k];
                xq[k] = *(const v2*)(pre + (size_t)k * 8192);
                float r0[8];
                ROTS8(h0p, r0);
                v2 a0L = __builtin_elementwise_fma(w0p[0], v2{r0[0], r0[0]}, xc);
                v2 a0H = w0p[4] * v2{r0[4], r0[4]};
                #pragma unroll
                for (int m = 1; m < 4; ++m) {
                    a0L = __builtin_elementwise_fma(w0p[m], v2{r0[m], r0[m]}, a0L);
                    a0H = __builtin_elementwise_fma(w0p[m + 4], v2{r0[m + 4], r0[m + 4]}, a0H);
                }
                v2 a0 = a0L + a0H;
                float eA = __builtin_amdgcn_exp2f(a0.x);
                float eB = __builtin_amdgcn_exp2f(a0.y);
                float tA = __builtin_amdgcn_rcpf(1.0f + eA);
                float tB = __builtin_fmaf(aB, __builtin_amdgcn_rcpf(1.0f + eB), bB);
                COMBINE2(tA, tB, c0v, h0p);
                ring0[sb8 + k][lt] = h0p;
                if (k == 3 || k == 7) __syncthreads();   // #1..#128
            }
        }
        __syncthreads();                                  // #129
        __syncthreads();                                  // #130
    } else if (wid == 1) {
        // ----- wave A2: a1p = b1 + Wih1*h0 -----
        v2 wi1p[8];
        #pragma unroll
        for (int m = 0; m < 8; ++m) {
            int k = j ^ m;
            wi1p[m] = v2{SSIG * w_ih1[gA * 8 + k], sB_ * w_ih1[gB * 8 + k]};
        }
        const v2 b1p = v2{SSIG * (b_ih1[gA] + b_hh1[gA]),
                          sB_  * (b_ih1[gB] + b_hh1[gB])};

        __syncthreads();                                  // #1
        for (int p = 1; p <= 128; ++p) {
            const int sb = ((p - 1) & 3) * 4;
            float h0v[4];
            #pragma unroll
            for (int k = 0; k < 4; ++k) h0v[k] = ring0[sb + k][lt];
            #pragma unroll
            for (int k = 0; k < 4; ++k) {
                float r0[8];
                ROTS8(h0v[k], r0);
                v2 a = __builtin_elementwise_fma(wi1p[0], v2{r0[0], r0[0]}, b1p);
                #pragma unroll
                for (int m = 1; m < 8; ++m)
                    a = __builtin_elementwise_fma(wi1p[m], v2{r0[m], r0[m]}, a);
                *(v2*)&ring1[sb + k][lt * 2] = a;
            }
            __syncthreads();                              // #2..#129
        }
        __syncthreads();                                  // #130
    } else if (wid == 2) {
        // ----- wave B: layer-1 recurrence -> ring2 -----
        v2 wh1p[8];
        #pragma unroll
        for (int m = 0; m < 8; ++m) {
            int k = j ^ m;
            wh1p[m] = v2{SSIG * w_hh1[gA * 8 + k], sB_ * w_hh1[gB * 8 + k]};
        }
        float h1p = 0.f, c1v = 0.f;

        auto BODY4 = [&](int p) {
            const int sb = ((p - 2) & 3) * 4;
            v2 a1in[4];
            #pragma unroll
            for (int k = 0; k < 4; ++k) a1in[k] = *(const v2*)&ring1[sb + k][lt * 2];
            #pragma unroll
            for (int k = 0; k < 4; ++k) {
                float r1[8];
                ROTS8(h1p, r1);
                v2 aL = __builtin_elementwise_fma(wh1p[0], v2{r1[0], r1[0]}, a1in[k]);
                v2 aH = wh1p[4] * v2{r1[4], r1[4]};
                #pragma unroll
                for (int m = 1; m < 4; ++m) {
                    aL = __builtin_elementwise_fma(wh1p[m], v2{r1[m], r1[m]}, aL);
                    aH = __builtin_elementwise_fma(wh1p[m + 4], v2{r1[m + 4], r1[m + 4]}, aH);
                }
                v2 a1 = aL + aH;
                float eA = __builtin_amdgcn_exp2f(a1.x);
                float eB = __builtin_amdgcn_exp2f(a1.y);
                float tA = __builtin_amdgcn_rcpf(1.0f + eA);
                float tB = __builtin_fmaf(aB, __builtin_amdgcn_rcpf(1.0f + eB), bB);
                COMBINE2(tA, tB, c1v, h1p);
                ring2[sb + k][lt] = h1p;
            }
        };

        __syncthreads();                                  // #1
        __syncthreads();                                  // #2
        for (int p = 2; p <= 128; ++p) { BODY4(p); __syncthreads(); }  // #3..#129
        BODY4(129);                                       // steps 508..511
        __syncthreads();                                  // #130
    } else {
        // ----- wave W3: projection -----
        float wrl[8];
        #pragma unroll
        for (int m = 0; m < 8; ++m) wrl[m] = w_reg[b3 * 8 + (j ^ m)];
        const float br  = b_reg[b3];
        const bool isl  = (j == 0);
        const int  ooff = (bid * 4 + cc) * 2 + b3;

        auto PBODY = [&](int sb, int wbase) {
            float h1v[4];
            #pragma unroll
            for (int k = 0; k < 4; ++k) h1v[k] = ring2[sb + k][lt];
            #pragma unroll
            for (int k = 0; k < 4; ++k) {
                float r1[8];
                ROTS8(h1v[k], r1);
                float pp = br;
                #pragma unroll
                for (int m = 0; m < 8; ++m) pp = __builtin_fmaf(wrl[m], r1[m], pp);
                if (isl) out[(size_t)(wbase + k) * 512 + ooff] = pp;
            }
        };

        __syncthreads();                                  // #1
        __syncthreads();                                  // #2
        __syncthreads();                                  // #3
        for (int p = 3; p <= 129; ++p) {
            PBODY(((p - 3) & 3) * 4, 4 * (p - 3));
            __syncthreads();                              // #4..#130
        }
        PBODY(12, 508);                                   // steps 508..511
    }
}

extern "C" void kernel_launch(void* const* d_in, const int* in_sizes, int n_in,
                              void* d_out, int out_size, void* d_ws, size_t ws_size,
                              hipStream_t stream) {
    (void)in_sizes; (void)n_in; (void)out_size; (void)ws_size;
    const float* x     = (const float*)d_in[0];
    const float* w_ih0 = (const float*)d_in[1];
    const float* w_hh0 = (const float*)d_in[2];
    const float* b_ih0 = (const float*)d_in[3];
    const float* b_hh0 = (const float*)d_in[4];
    const float* w_ih1 = (const float*)d_in[5];
    const float* w_hh1 = (const float*)d_in[6];
    const float* b_ih1 = (const float*)d_in[7];
    const float* b_hh1 = (const float*)d_in[8];
    const float* w_reg = (const float*)d_in[9];
    const float* b_reg = (const float*)d_in[10];
    float* out = (float*)d_out;
    float* xg2 = (float*)d_ws;   // 512*64*128*4 = 16 MB scratch

    xg_gemm<<<1024, 256, 0, stream>>>(x, w_ih0, b_ih0, b_hh0, xg2);
    lstm_scan<<<64, 256, 0, stream>>>(xg2, w_hh0, w_ih1, w_hh1, b_ih1, b_hh1,
                                      w_reg, b_reg, out);
}